// Round 5
// baseline (430.616 us; speedup 1.0000x reference)
//
#include <hip/hip_runtime.h>
#include <hip/hip_bf16.h>

// ScaledDotAttention: out = softmax_causal((X Wq)(X Wk)^T / 32) (X Wv) Wo + bo
// B=8, T=2048, D=DK=DV=1024. bf16 MFMA pipeline, materialized S/P in ws.
// R5: 256x256 tile, 512 thr / 8 waves (2Mx4N), 64 MFMA per barrier, 128 KiB
//     LDS double-buffer, same 2-phase sync structure as R4. f32 inputs
//     pre-converted to bf16 (uniform bf16-A GEMM); softmax write boundary
//     moved to 256 alignment to match PV K-clamp.

typedef __attribute__((ext_vector_type(8))) short bf16x8;
typedef __attribute__((ext_vector_type(4))) float f32x4;

#define DEVI __device__ __forceinline__

DEVI unsigned short f2bf(float f) {
  union { float f; unsigned u; } v; v.f = f;
  unsigned r = v.u + 0x7FFFu + ((v.u >> 16) & 1u);
  return (unsigned short)(r >> 16);
}

DEVI void load_lds16(const void* g, void* l) {
  __builtin_amdgcn_global_load_lds(
      (const __attribute__((address_space(1))) unsigned int*)g,
      (__attribute__((address_space(3))) unsigned int*)l,
      16, 0, 0);
}

constexpr int BM = 256, BN = 256, BK = 64;

// C[M][N] = A[M][K] * Bt[N][K]^T  (A bf16, Bt bf16 stored row=n contiguous k).
// LDS layout: chunk (row, slot) at row*128 + ((slot^(row&7))<<4), staged via
// global_load_lds with pre-swizzled source (rule #21: both sides same XOR).
template<bool OUT_F32, bool OUT_TRANS, bool DO_BIAS, bool DO_SCALE,
         bool DO_CSKIP, bool DO_KCLAMP>
__global__ __launch_bounds__(512, 2) void gemm_k(
    const unsigned short* __restrict__ Ab, long lda, long sAz,
    const unsigned short* __restrict__ Bt, long ldb, long sBz,
    void* __restrict__ Cp, long ldc, long sCz,
    const float* __restrict__ bias, float scale,
    const int* __restrict__ maskp, int Kdim)
{
  // bijective XCD-chunked block swizzle (all grids have nwg % 8 == 0)
  const int nx = gridDim.x, ny = gridDim.y;
  int bid = (blockIdx.z * ny + blockIdx.y) * nx + blockIdx.x;
  const int nwg = nx * ny * (int)gridDim.z;
  if ((nwg & 7) == 0) bid = (bid & 7) * (nwg >> 3) + (bid >> 3);
  const int bx = bid % nx;
  const int t1 = bid / nx;
  const int by = t1 % ny;
  const int z  = t1 / ny;

  const int n0 = bx * BN;
  const int m0 = by * BM;
  if constexpr (DO_CSKIP) {
    if (maskp[0] && n0 > m0 + (BM - 1)) return;  // tile fully above diagonal
  }
  int Keff = Kdim;
  if constexpr (DO_KCLAMP) {
    if (maskp[0]) Keff = min(Kdim, m0 + BM);     // P lower-triangular
  }

  __shared__ unsigned short As[2][BM * BK];  // 32 KiB each
  __shared__ unsigned short Bs[2][BN * BK];  // 32 KiB each -> 128 KiB total

  const int tid  = threadIdx.x;
  const int lane = tid & 63;
  const int w    = tid >> 6;
  const int wr   = w >> 2, wc = w & 3;   // 2x4 waves; per-wave 128(M) x 64(N)

  f32x4 acc[8][4];
  const f32x4 z4 = {0.f, 0.f, 0.f, 0.f};
#pragma unroll
  for (int mi = 0; mi < 8; ++mi)
#pragma unroll
    for (int ni = 0; ni < 4; ++ni) acc[mi][ni] = z4;

  const unsigned short* Ag0 = Ab + (size_t)z * sAz + (size_t)m0 * lda;
  const unsigned short* Bg0 = Bt + (size_t)z * sBz + (size_t)n0 * ldb;

  // stage one K-tile (A 256x64 + B 256x64 bf16) into buffer `buf`
  auto stage = [&](int buf, int k0) {
#pragma unroll
    for (int p = 0; p < 4; ++p) {
      int cb = p * 512 + w * 64;                  // wave-uniform chunk base
      int c  = cb + lane;
      int row = c >> 3, gs = (c & 7) ^ (row & 7); // pre-swizzled source slot
      load_lds16(Ag0 + (size_t)row * lda + k0 + gs * 8, (char*)As[buf] + cb * 16);
    }
#pragma unroll
    for (int p = 0; p < 4; ++p) {
      int cb = p * 512 + w * 64;
      int c  = cb + lane;
      int row = c >> 3, gs = (c & 7) ^ (row & 7);
      load_lds16(Bg0 + (size_t)row * ldb + k0 + gs * 8, (char*)Bs[buf] + cb * 16);
    }
  };

  stage(0, 0);
  __syncthreads();  // tile 0 resident

  const int nt = Keff / BK;
  int cur = 0;
  for (int t = 0; t < nt; ++t) {
    if (t + 1 < nt) stage(cur ^ 1, (t + 1) * BK);   // overlap under MFMA

#pragma unroll
    for (int kk = 0; kk < 2; ++kk) {
      bf16x8 af[8], bfv[4];
#pragma unroll
      for (int mi = 0; mi < 8; ++mi) {
        int r = wr * 128 + mi * 16 + (lane & 15);
        int slot = kk * 4 + (lane >> 4);
        af[mi] = *(const bf16x8*)((const char*)As[cur] + r * 128 + ((slot ^ (r & 7)) << 4));
      }
#pragma unroll
      for (int ni = 0; ni < 4; ++ni) {
        int r = wc * 64 + ni * 16 + (lane & 15);
        int slot = kk * 4 + (lane >> 4);
        bfv[ni] = *(const bf16x8*)((const char*)Bs[cur] + r * 128 + ((slot ^ (r & 7)) << 4));
      }
      __builtin_amdgcn_s_setprio(1);
#pragma unroll
      for (int mi = 0; mi < 8; ++mi)
#pragma unroll
        for (int ni = 0; ni < 4; ++ni)
          acc[mi][ni] = __builtin_amdgcn_mfma_f32_16x16x32_bf16(af[mi], bfv[ni], acc[mi][ni], 0, 0, 0);
      __builtin_amdgcn_s_setprio(0);
    }
    __syncthreads();  // drains vmcnt+lgkm; next tile resident
    cur ^= 1;
  }

  // epilogue: D frag (verified m89): col = lane&15, row = (lane>>4)*4 + reg
#pragma unroll
  for (int ni = 0; ni < 4; ++ni) {
    const int n = n0 + wc * 64 + ni * 16 + (lane & 15);
    float bv = 0.f;
    if constexpr (DO_BIAS) bv = bias[n];
#pragma unroll
    for (int mi = 0; mi < 8; ++mi) {
      const int m = m0 + wr * 128 + mi * 16 + ((lane >> 4) << 2);
      f32x4 c = acc[mi][ni];
      if constexpr (DO_SCALE) c = c * scale;
      if constexpr (DO_BIAS)  c = c + bv;
      if constexpr (OUT_TRANS) {
        unsigned short* C = (unsigned short*)Cp + (size_t)z * sCz + (size_t)n * ldc + m;
        ushort4 h;
        h.x = f2bf(c[0]); h.y = f2bf(c[1]); h.z = f2bf(c[2]); h.w = f2bf(c[3]);
        *(ushort4*)C = h;
      } else if constexpr (OUT_F32) {
        float* C = (float*)Cp + (size_t)z * sCz + (size_t)m * ldc + n;
#pragma unroll
        for (int j = 0; j < 4; ++j) C[(size_t)j * ldc] = c[j];
      } else {
        unsigned short* C = (unsigned short*)Cp + (size_t)z * sCz + (size_t)m * ldc + n;
#pragma unroll
        for (int j = 0; j < 4; ++j) C[(size_t)j * ldc] = f2bf(c[j]);
      }
    }
  }
}

// f32 -> bf16 bulk convert: query/keys/values (z = which tensor)
__global__ __launch_bounds__(256) void cvt_k(
    const float* __restrict__ q, const float* __restrict__ k,
    const float* __restrict__ v, unsigned short* __restrict__ xq,
    unsigned short* __restrict__ xk, unsigned short* __restrict__ xv)
{
  const float* s = blockIdx.y == 0 ? q : blockIdx.y == 1 ? k : v;
  unsigned short* d = blockIdx.y == 0 ? xq : blockIdx.y == 1 ? xk : xv;
  const long n4 = 8l * 2048 * 1024 / 4;
  for (long i = (long)blockIdx.x * 256 + threadIdx.x; i < n4;
       i += (long)gridDim.x * 256) {
    float4 a = *(const float4*)(s + i * 4);
    ushort4 h;
    h.x = f2bf(a.x); h.y = f2bf(a.y); h.z = f2bf(a.z); h.w = f2bf(a.w);
    *(ushort4*)(d + i * 4) = h;
  }
}

// Wt[n][k] = bf16(W[k][n]), 1024x1024, 64x64 tiles via LDS
__global__ __launch_bounds__(256) void wtrans_k(const float* __restrict__ W,
                                                unsigned short* __restrict__ Wt)
{
  __shared__ unsigned short L[64][80];  // 160B row stride, 16B aligned
  const int n0 = blockIdx.x * 64, k0 = blockIdx.y * 64;
  const int tid = threadIdx.x;
#pragma unroll
  for (int p = 0; p < 4; ++p) {
    int idx = tid + p * 256;
    int r = idx >> 4, c4 = idx & 15;
    float4 v = *(const float4*)(W + (size_t)(k0 + r) * 1024 + n0 + c4 * 4);
    L[c4 * 4 + 0][r] = f2bf(v.x);
    L[c4 * 4 + 1][r] = f2bf(v.y);
    L[c4 * 4 + 2][r] = f2bf(v.z);
    L[c4 * 4 + 3][r] = f2bf(v.w);
  }
  __syncthreads();
#pragma unroll
  for (int p = 0; p < 2; ++p) {
    int idx = tid + p * 256;
    int n = idx >> 3, c8 = idx & 7;
    int4 v = *(const int4*)(&L[n][c8 * 8]);
    *(int4*)(Wt + (size_t)(n0 + n) * 1024 + k0 + c8 * 8) = v;
  }
}

// row softmax over S[16384][2048] f32; writes bf16 P in place (row-start).
// Causal: read only cols < lim; write zeros up to the 256-tile boundary
// (PV's K-clamp with BM=256 never reads beyond it).
__global__ __launch_bounds__(256) void softmax_k(float* __restrict__ S,
                                                 const int* __restrict__ maskp)
{
  const int row = blockIdx.x;
  const int t = row & 2047;
  const int msk = maskp[0];
  const int lim  = msk ? (t + 1) : 2048;
  const int wlim = msk ? ((t & ~255) + 256) : 2048;
  float* Srow = S + (size_t)row * 2048;
  const int tid = threadIdx.x;
  const int cbase = tid * 8;

  float v[8];
  if (cbase < lim) {
    float4 a = *(const float4*)(Srow + cbase);
    float4 b = *(const float4*)(Srow + cbase + 4);
    v[0] = a.x; v[1] = a.y; v[2] = a.z; v[3] = a.w;
    v[4] = b.x; v[5] = b.y; v[6] = b.z; v[7] = b.w;
#pragma unroll
    for (int j = 0; j < 8; ++j)
      if (cbase + j >= lim) v[j] = -__builtin_inff();
  } else {
#pragma unroll
    for (int j = 0; j < 8; ++j) v[j] = -__builtin_inff();
  }

  float mx = v[0];
#pragma unroll
  for (int j = 1; j < 8; ++j) mx = fmaxf(mx, v[j]);
#pragma unroll
  for (int off = 32; off; off >>= 1) mx = fmaxf(mx, __shfl_xor(mx, off, 64));

  __shared__ float redm[4], reds[4];
  const int wid = tid >> 6;
  if ((tid & 63) == 0) redm[wid] = mx;
  __syncthreads();  // also orders all row loads before the in-place write below
  mx = fmaxf(fmaxf(redm[0], redm[1]), fmaxf(redm[2], redm[3]));

  float e[8], s = 0.f;
#pragma unroll
  for (int j = 0; j < 8; ++j) { e[j] = __expf(v[j] - mx); s += e[j]; }
#pragma unroll
  for (int off = 32; off; off >>= 1) s += __shfl_xor(s, off, 64);
  if ((tid & 63) == 0) reds[wid] = s;
  __syncthreads();
  s = reds[0] + reds[1] + reds[2] + reds[3];
  const float inv = 1.0f / s;

  if (cbase < wlim) {
    unsigned short* Prow = (unsigned short*)Srow;
    unsigned pk[4];
#pragma unroll
    for (int q = 0; q < 4; ++q)
      pk[q] = (unsigned)f2bf(e[2 * q] * inv) | ((unsigned)f2bf(e[2 * q + 1] * inv) << 16);
    int4 o; o.x = (int)pk[0]; o.y = (int)pk[1]; o.z = (int)pk[2]; o.w = (int)pk[3];
    *(int4*)(Prow + (size_t)cbase) = o;
  }
}

extern "C" void kernel_launch(void* const* d_in, const int* in_sizes, int n_in,
                              void* d_out, int out_size, void* d_ws, size_t ws_size,
                              hipStream_t stream)
{
  const float* query  = (const float*)d_in[0];
  const float* keys   = (const float*)d_in[1];
  const float* values = (const float*)d_in[2];
  const float* Wq = (const float*)d_in[3];
  const float* bq = (const float*)d_in[4];
  const float* Wk = (const float*)d_in[5];
  const float* bk = (const float*)d_in[6];
  const float* Wv = (const float*)d_in[7];
  const float* bv = (const float*)d_in[8];
  const float* Wo = (const float*)d_in[9];
  const float* bo = (const float*)d_in[10];
  const int* maskp = (const int*)d_in[11];
  float* out = (float*)d_out;

  char* ws = (char*)d_ws;
  const size_t MB = 1ull << 20;
  unsigned short* wt_q = (unsigned short*)(ws + 0 * MB);
  unsigned short* wt_k = (unsigned short*)(ws + 2 * MB);
  unsigned short* wt_v = (unsigned short*)(ws + 4 * MB);
  unsigned short* wt_o = (unsigned short*)(ws + 6 * MB);
  unsigned short* Qb   = (unsigned short*)(ws + 8 * MB);    // 32 MiB [16384][1024]
  unsigned short* Kb   = (unsigned short*)(ws + 40 * MB);   // 32 MiB
  unsigned short* Vt   = (unsigned short*)(ws + 72 * MB);   // 32 MiB [8][1024][2048]
  float*          S    = (float*)(ws + 104 * MB);           // 128 MiB [16384][2048]
  // bf16 copies of query/keys/values alias the S region (dead before scores)
  unsigned short* Xq   = (unsigned short*)(ws + 104 * MB);  // 32 MiB
  unsigned short* Xk   = (unsigned short*)(ws + 136 * MB);  // 32 MiB
  unsigned short* Xv   = (unsigned short*)(ws + 168 * MB);  // 32 MiB
  unsigned short* ctx  = Qb;  // context aliases Q (Q dead after scores)

  const dim3 blk(512);
  const long sXT = 2048l * 1024;   // per-batch stride of [T,1024] tensors

  // weight transpose+convert, input f32->bf16 convert
  wtrans_k<<<dim3(16, 16), dim3(256), 0, stream>>>(Wq, wt_q);
  wtrans_k<<<dim3(16, 16), dim3(256), 0, stream>>>(Wk, wt_k);
  wtrans_k<<<dim3(16, 16), dim3(256), 0, stream>>>(Wv, wt_v);
  wtrans_k<<<dim3(16, 16), dim3(256), 0, stream>>>(Wo, wt_o);
  cvt_k<<<dim3(4096, 3), dim3(256), 0, stream>>>(query, keys, values, Xq, Xk, Xv);

  // projections (bf16 A). V written transposed per batch.
  gemm_k<false, false, true, false, false, false><<<dim3(4, 8, 8), blk, 0, stream>>>(
      Xq, 1024, sXT, wt_q, 1024, 0, Qb, 1024, sXT, bq, 1.f, nullptr, 1024);
  gemm_k<false, false, true, false, false, false><<<dim3(4, 8, 8), blk, 0, stream>>>(
      Xk, 1024, sXT, wt_k, 1024, 0, Kb, 1024, sXT, bk, 1.f, nullptr, 1024);
  gemm_k<false, true, true, false, false, false><<<dim3(4, 8, 8), blk, 0, stream>>>(
      Xv, 1024, sXT, wt_v, 1024, 0, Vt, 2048, 1024l * 2048, bv, 1.f, nullptr, 1024);

  // scores: S[b][t][s] = Q[b] K[b]^T / 32, upper tiles skipped when masked
  gemm_k<true, false, false, true, true, false><<<dim3(8, 8, 8), blk, 0, stream>>>(
      Qb, 1024, sXT, Kb, 1024, sXT, S, 2048, 2048l * 2048, nullptr, 0.03125f, maskp, 1024);

  // softmax rows -> bf16 P in place (stride 4096 elems)
  softmax_k<<<dim3(16384), dim3(256), 0, stream>>>(S, maskp);

  // context[b][t][d] = P[b] @ V[b]  (A = P bf16, lda 4096; Bt = Vt; K causal-clamped)
  gemm_k<false, false, false, false, false, true><<<dim3(4, 8, 8), blk, 0, stream>>>(
      (unsigned short*)S, 4096, 2048l * 4096, Vt, 2048, 1024l * 2048,
      ctx, 1024, sXT, nullptr, 1.f, maskp, 2048);

  // out = context @ Wo + bo (f32 out)
  gemm_k<true, false, true, false, false, false><<<dim3(4, 8, 8), blk, 0, stream>>>(
      ctx, 1024, sXT, wt_o, 1024, 0, out, 1024, sXT, bo, 1.f, nullptr, 1024);
}

// Round 6
// 374.268 us; speedup vs baseline: 1.1506x; 1.1506x over previous
//
#include <hip/hip_runtime.h>
#include <hip/hip_bf16.h>

// ScaledDotAttention: out = softmax_causal((X Wq)(X Wk)^T / 32) (X Wv) Wo + bo
// B=8, T=2048, D=DK=DV=1024. bf16 MFMA pipeline, materialized S/P in ws.
// R6: 8-phase counted-vmcnt schedule (T3+T4) in gemm_k. 4 phases/K-tile,
//     16 MFMA/phase, one half-chunk stage issue per phase, vmcnt(4) gates
//     (never 0 in steady state), raw s_barrier per phase. LDS: 2buf x {A,B}
//     x 2 K-halves x 16KB, slot' = (q+(r>>1))&3 permutation (2-way = free).

typedef __attribute__((ext_vector_type(8))) short bf16x8;
typedef __attribute__((ext_vector_type(4))) float f32x4;

#define DEVI __device__ __forceinline__
#define VM_GATE(n) asm volatile("s_waitcnt vmcnt(" #n ")" ::: "memory")

DEVI unsigned short f2bf(float f) {
  union { float f; unsigned u; } v; v.f = f;
  unsigned r = v.u + 0x7FFFu + ((v.u >> 16) & 1u);
  return (unsigned short)(r >> 16);
}

DEVI void load_lds16(const void* g, void* l) {
  __builtin_amdgcn_global_load_lds(
      (const __attribute__((address_space(1))) unsigned int*)g,
      (__attribute__((address_space(3))) unsigned int*)l,
      16, 0, 0);
}

constexpr int BM = 256, BN = 256, BK = 64;

// Stage one 16KB chunk ([256 rows][32 K] bf16) = 2 global_load_lds per thread.
// LDS linear tloc=(r*4+ps) holds global k-slot q=(ps-(r>>1))&3 (inverse of the
// read-side permutation slot'=(q+(r>>1))&3).
DEVI void stage_chunk(char* chunk, const unsigned short* src, long ldx,
                      int kbase, int tid) {
#pragma unroll
  for (int i = 0; i < 2; ++i) {
    int tloc = i * 512 + tid;
    int r = tloc >> 2, ps = tloc & 3;
    int q = (ps - (r >> 1)) & 3;
    load_lds16(src + (size_t)r * ldx + kbase + q * 8,
               chunk + (i * 512 + (tid & 0x1C0)) * 16);
  }
}

// read one 16B fragment at row r, k-group q0 from a chunk
DEVI bf16x8 frag(const char* chunk, int r, int q0) {
  int sp = (q0 + (r >> 1)) & 3;
  return *(const bf16x8*)(chunk + r * 64 + sp * 16);
}

// C[M][N] = A[M][K] * Bt[N][K]^T  (A bf16, Bt bf16 stored row=n contiguous k)
template<bool OUT_F32, bool OUT_TRANS, bool DO_BIAS, bool DO_SCALE,
         bool DO_CSKIP, bool DO_KCLAMP>
__global__ __launch_bounds__(512, 2) void gemm_k(
    const unsigned short* __restrict__ Ab, long lda, long sAz,
    const unsigned short* __restrict__ Bt, long ldb, long sBz,
    void* __restrict__ Cp, long ldc, long sCz,
    const float* __restrict__ bias, float scale,
    const int* __restrict__ maskp, int Kdim)
{
  // bijective XCD-chunked block swizzle (all grids have nwg % 8 == 0)
  const int nx = gridDim.x, ny = gridDim.y;
  int bid = (blockIdx.z * ny + blockIdx.y) * nx + blockIdx.x;
  const int nwg = nx * ny * (int)gridDim.z;
  if ((nwg & 7) == 0) bid = (bid & 7) * (nwg >> 3) + (bid >> 3);
  const int bx = bid % nx;
  const int t1 = bid / nx;
  const int by = t1 % ny;
  const int z  = t1 / ny;

  const int n0 = bx * BN;
  const int m0 = by * BM;
  if constexpr (DO_CSKIP) {
    if (maskp[0] && n0 > m0 + (BM - 1)) return;  // tile fully above diagonal
  }
  int Keff = Kdim;
  if constexpr (DO_KCLAMP) {
    if (maskp[0]) Keff = min(Kdim, m0 + BM);     // P lower-triangular
  }

  // [buf][tensor A=0/B=1][k-half][16KB]
  __shared__ alignas(16) char LDSb[2][2][2][16384];

  const int tid  = threadIdx.x;
  const int lane = tid & 63;
  const int w    = tid >> 6;
  const int wr   = w >> 2, wc = w & 3;   // 2x4 waves; per-wave 128(M) x 64(N)
  const int la   = lane & 15;
  const int q0   = lane >> 4;

  f32x4 acc[8][4];
  const f32x4 z4 = {0.f, 0.f, 0.f, 0.f};
#pragma unroll
  for (int mi = 0; mi < 8; ++mi)
#pragma unroll
    for (int ni = 0; ni < 4; ++ni) acc[mi][ni] = z4;

  const unsigned short* Ag0 = Ab + (size_t)z * sAz + (size_t)m0 * lda;
  const unsigned short* Bg0 = Bt + (size_t)z * sBz + (size_t)n0 * ldb;

  // prologue: stage all 4 chunks of tile 0 (issue order = consumption order)
  stage_chunk(LDSb[0][0][0], Ag0, lda, 0,  tid);
  stage_chunk(LDSb[0][1][0], Bg0, ldb, 0,  tid);
  stage_chunk(LDSb[0][0][1], Ag0, lda, 32, tid);
  stage_chunk(LDSb[0][1][1], Bg0, ldb, 32, tid);

  const int nt = Keff / BK;
  for (int t = 0; t < nt; ++t) {
    const int buf = t & 1, nb = buf ^ 1;
    const bool pf = (t + 1 < nt);
    const int kb = (t + 1) * BK;
    const char* Ak0 = LDSb[buf][0][0];
    const char* Bk0 = LDSb[buf][1][0];
    const char* Ak1 = LDSb[buf][0][1];
    const char* Bk1 = LDSb[buf][1][1];
    bf16x8 bfv0[4], bfv1[4], af[4];

    // ---- phase A: kk0, mi 0-3. Gate K0(t) chunks (oldest 4 loads).
    VM_GATE(4);
    __builtin_amdgcn_s_barrier();
    __builtin_amdgcn_sched_barrier(0);
#pragma unroll
    for (int ni = 0; ni < 4; ++ni) bfv0[ni] = frag(Bk0, wc * 64 + ni * 16 + la, q0);
#pragma unroll
    for (int mi = 0; mi < 4; ++mi) af[mi] = frag(Ak0, wr * 128 + mi * 16 + la, q0);
    if (pf) stage_chunk((char*)LDSb[nb][0][0], Ag0, lda, kb, tid);
    __builtin_amdgcn_s_setprio(1);
#pragma unroll
    for (int mi = 0; mi < 4; ++mi)
#pragma unroll
      for (int ni = 0; ni < 4; ++ni)
        acc[mi][ni] = __builtin_amdgcn_mfma_f32_16x16x32_bf16(af[mi], bfv0[ni], acc[mi][ni], 0, 0, 0);
    __builtin_amdgcn_s_setprio(0);

    // ---- phase B: kk0, mi 4-7 (reuse bfv0)
    __builtin_amdgcn_s_barrier();
    __builtin_amdgcn_sched_barrier(0);
#pragma unroll
    for (int mi = 0; mi < 4; ++mi) af[mi] = frag(Ak0, wr * 128 + 64 + mi * 16 + la, q0);
    if (pf) stage_chunk((char*)LDSb[nb][1][0], Bg0, ldb, kb, tid);
    __builtin_amdgcn_s_setprio(1);
#pragma unroll
    for (int mi = 0; mi < 4; ++mi)
#pragma unroll
      for (int ni = 0; ni < 4; ++ni)
        acc[4 + mi][ni] = __builtin_amdgcn_mfma_f32_16x16x32_bf16(af[mi], bfv0[ni], acc[4 + mi][ni], 0, 0, 0);
    __builtin_amdgcn_s_setprio(0);

    // ---- phase C: kk1, mi 0-3. Gate K1(t): 4 outstanding if last tile.
    if (pf) { VM_GATE(4); } else { VM_GATE(0); }
    __builtin_amdgcn_s_barrier();
    __builtin_amdgcn_sched_barrier(0);
#pragma unroll
    for (int ni = 0; ni < 4; ++ni) bfv1[ni] = frag(Bk1, wc * 64 + ni * 16 + la, q0);
#pragma unroll
    for (int mi = 0; mi < 4; ++mi) af[mi] = frag(Ak1, wr * 128 + mi * 16 + la, q0);
    if (pf) stage_chunk((char*)LDSb[nb][0][1], Ag0, lda, kb + 32, tid);
    __builtin_amdgcn_s_setprio(1);
#pragma unroll
    for (int mi = 0; mi < 4; ++mi)
#pragma unroll
      for (int ni = 0; ni < 4; ++ni)
        acc[mi][ni] = __builtin_amdgcn_mfma_f32_16x16x32_bf16(af[mi], bfv1[ni], acc[mi][ni], 0, 0, 0);
    __builtin_amdgcn_s_setprio(0);

    // ---- phase D: kk1, mi 4-7 (reuse bfv1)
    __builtin_amdgcn_s_barrier();
    __builtin_amdgcn_sched_barrier(0);
#pragma unroll
    for (int mi = 0; mi < 4; ++mi) af[mi] = frag(Ak1, wr * 128 + 64 + mi * 16 + la, q0);
    if (pf) stage_chunk((char*)LDSb[nb][1][1], Bg0, ldb, kb + 32, tid);
    __builtin_amdgcn_s_setprio(1);
#pragma unroll
    for (int mi = 0; mi < 4; ++mi)
#pragma unroll
      for (int ni = 0; ni < 4; ++ni)
        acc[4 + mi][ni] = __builtin_amdgcn_mfma_f32_16x16x32_bf16(af[mi], bfv1[ni], acc[4 + mi][ni], 0, 0, 0);
    __builtin_amdgcn_s_setprio(0);
  }

  // epilogue: D frag (verified m89): col = lane&15, row = (lane>>4)*4 + reg
#pragma unroll
  for (int ni = 0; ni < 4; ++ni) {
    const int n = n0 + wc * 64 + ni * 16 + la;
    float bv = 0.f;
    if constexpr (DO_BIAS) bv = bias[n];
#pragma unroll
    for (int mi = 0; mi < 8; ++mi) {
      const int m = m0 + wr * 128 + mi * 16 + (q0 << 2);
      f32x4 c = acc[mi][ni];
      if constexpr (DO_SCALE) c = c * scale;
      if constexpr (DO_BIAS)  c = c + bv;
      if constexpr (OUT_TRANS) {
        unsigned short* C = (unsigned short*)Cp + (size_t)z * sCz + (size_t)n * ldc + m;
        ushort4 h;
        h.x = f2bf(c[0]); h.y = f2bf(c[1]); h.z = f2bf(c[2]); h.w = f2bf(c[3]);
        *(ushort4*)C = h;
      } else if constexpr (OUT_F32) {
        float* C = (float*)Cp + (size_t)z * sCz + (size_t)m * ldc + n;
#pragma unroll
        for (int j = 0; j < 4; ++j) C[(size_t)j * ldc] = c[j];
      } else {
        unsigned short* C = (unsigned short*)Cp + (size_t)z * sCz + (size_t)m * ldc + n;
#pragma unroll
        for (int j = 0; j < 4; ++j) C[(size_t)j * ldc] = f2bf(c[j]);
      }
    }
  }
}

// f32 -> bf16 bulk convert: query/keys/values
__global__ __launch_bounds__(256) void cvt_k(
    const float* __restrict__ q, const float* __restrict__ k,
    const float* __restrict__ v, unsigned short* __restrict__ xq,
    unsigned short* __restrict__ xk, unsigned short* __restrict__ xv)
{
  const float* s = blockIdx.y == 0 ? q : blockIdx.y == 1 ? k : v;
  unsigned short* d = blockIdx.y == 0 ? xq : blockIdx.y == 1 ? xk : xv;
  const long n4 = 8l * 2048 * 1024 / 4;
  for (long i = (long)blockIdx.x * 256 + threadIdx.x; i < n4;
       i += (long)gridDim.x * 256) {
    float4 a = *(const float4*)(s + i * 4);
    ushort4 h;
    h.x = f2bf(a.x); h.y = f2bf(a.y); h.z = f2bf(a.z); h.w = f2bf(a.w);
    *(ushort4*)(d + i * 4) = h;
  }
}

// Wt[n][k] = bf16(W[k][n]), 1024x1024, 64x64 tiles via LDS
__global__ __launch_bounds__(256) void wtrans_k(const float* __restrict__ W,
                                                unsigned short* __restrict__ Wt)
{
  __shared__ unsigned short L[64][80];  // 160B row stride, 16B aligned
  const int n0 = blockIdx.x * 64, k0 = blockIdx.y * 64;
  const int tid = threadIdx.x;
#pragma unroll
  for (int p = 0; p < 4; ++p) {
    int idx = tid + p * 256;
    int r = idx >> 4, c4 = idx & 15;
    float4 v = *(const float4*)(W + (size_t)(k0 + r) * 1024 + n0 + c4 * 4);
    L[c4 * 4 + 0][r] = f2bf(v.x);
    L[c4 * 4 + 1][r] = f2bf(v.y);
    L[c4 * 4 + 2][r] = f2bf(v.z);
    L[c4 * 4 + 3][r] = f2bf(v.w);
  }
  __syncthreads();
#pragma unroll
  for (int p = 0; p < 2; ++p) {
    int idx = tid + p * 256;
    int n = idx >> 3, c8 = idx & 7;
    int4 v = *(const int4*)(&L[n][c8 * 8]);
    *(int4*)(Wt + (size_t)(n0 + n) * 1024 + k0 + c8 * 8) = v;
  }
}

// row softmax over S[16384][2048] f32; writes bf16 P in place (row-start).
// Causal: read only cols < lim; write zeros up to the 256-tile boundary
// (PV's K-clamp with BM=256 never reads beyond it).
__global__ __launch_bounds__(256) void softmax_k(float* __restrict__ S,
                                                 const int* __restrict__ maskp)
{
  const int row = blockIdx.x;
  const int t = row & 2047;
  const int msk = maskp[0];
  const int lim  = msk ? (t + 1) : 2048;
  const int wlim = msk ? ((t & ~255) + 256) : 2048;
  float* Srow = S + (size_t)row * 2048;
  const int tid = threadIdx.x;
  const int cbase = tid * 8;

  float v[8];
  if (cbase < lim) {
    float4 a = *(const float4*)(Srow + cbase);
    float4 b = *(const float4*)(Srow + cbase + 4);
    v[0] = a.x; v[1] = a.y; v[2] = a.z; v[3] = a.w;
    v[4] = b.x; v[5] = b.y; v[6] = b.z; v[7] = b.w;
#pragma unroll
    for (int j = 0; j < 8; ++j)
      if (cbase + j >= lim) v[j] = -__builtin_inff();
  } else {
#pragma unroll
    for (int j = 0; j < 8; ++j) v[j] = -__builtin_inff();
  }

  float mx = v[0];
#pragma unroll
  for (int j = 1; j < 8; ++j) mx = fmaxf(mx, v[j]);
#pragma unroll
  for (int off = 32; off; off >>= 1) mx = fmaxf(mx, __shfl_xor(mx, off, 64));

  __shared__ float redm[4], reds[4];
  const int wid = tid >> 6;
  if ((tid & 63) == 0) redm[wid] = mx;
  __syncthreads();  // also orders all row loads before the in-place write below
  mx = fmaxf(fmaxf(redm[0], redm[1]), fmaxf(redm[2], redm[3]));

  float e[8], s = 0.f;
#pragma unroll
  for (int j = 0; j < 8; ++j) { e[j] = __expf(v[j] - mx); s += e[j]; }
#pragma unroll
  for (int off = 32; off; off >>= 1) s += __shfl_xor(s, off, 64);
  if ((tid & 63) == 0) reds[wid] = s;
  __syncthreads();
  s = reds[0] + reds[1] + reds[2] + reds[3];
  const float inv = 1.0f / s;

  if (cbase < wlim) {
    unsigned short* Prow = (unsigned short*)Srow;
    unsigned pk[4];
#pragma unroll
    for (int q = 0; q < 4; ++q)
      pk[q] = (unsigned)f2bf(e[2 * q] * inv) | ((unsigned)f2bf(e[2 * q + 1] * inv) << 16);
    int4 o; o.x = (int)pk[0]; o.y = (int)pk[1]; o.z = (int)pk[2]; o.w = (int)pk[3];
    *(int4*)(Prow + (size_t)cbase) = o;
  }
}

extern "C" void kernel_launch(void* const* d_in, const int* in_sizes, int n_in,
                              void* d_out, int out_size, void* d_ws, size_t ws_size,
                              hipStream_t stream)
{
  const float* query  = (const float*)d_in[0];
  const float* keys   = (const float*)d_in[1];
  const float* values = (const float*)d_in[2];
  const float* Wq = (const float*)d_in[3];
  const float* bq = (const float*)d_in[4];
  const float* Wk = (const float*)d_in[5];
  const float* bk = (const float*)d_in[6];
  const float* Wv = (const float*)d_in[7];
  const float* bv = (const float*)d_in[8];
  const float* Wo = (const float*)d_in[9];
  const float* bo = (const float*)d_in[10];
  const int* maskp = (const int*)d_in[11];
  float* out = (float*)d_out;

  char* ws = (char*)d_ws;
  const size_t MB = 1ull << 20;
  unsigned short* wt_q = (unsigned short*)(ws + 0 * MB);
  unsigned short* wt_k = (unsigned short*)(ws + 2 * MB);
  unsigned short* wt_v = (unsigned short*)(ws + 4 * MB);
  unsigned short* wt_o = (unsigned short*)(ws + 6 * MB);
  unsigned short* Qb   = (unsigned short*)(ws + 8 * MB);    // 32 MiB [16384][1024]
  unsigned short* Kb   = (unsigned short*)(ws + 40 * MB);   // 32 MiB
  unsigned short* Vt   = (unsigned short*)(ws + 72 * MB);   // 32 MiB [8][1024][2048]
  float*          S    = (float*)(ws + 104 * MB);           // 128 MiB [16384][2048]
  // bf16 copies of query/keys/values alias the S region (dead before scores)
  unsigned short* Xq   = (unsigned short*)(ws + 104 * MB);  // 32 MiB
  unsigned short* Xk   = (unsigned short*)(ws + 136 * MB);  // 32 MiB
  unsigned short* Xv   = (unsigned short*)(ws + 168 * MB);  // 32 MiB
  unsigned short* ctx  = Qb;  // context aliases Q (Q dead after scores)

  const dim3 blk(512);
  const long sXT = 2048l * 1024;   // per-batch stride of [T,1024] tensors

  // weight transpose+convert, input f32->bf16 convert
  wtrans_k<<<dim3(16, 16), dim3(256), 0, stream>>>(Wq, wt_q);
  wtrans_k<<<dim3(16, 16), dim3(256), 0, stream>>>(Wk, wt_k);
  wtrans_k<<<dim3(16, 16), dim3(256), 0, stream>>>(Wv, wt_v);
  wtrans_k<<<dim3(16, 16), dim3(256), 0, stream>>>(Wo, wt_o);
  cvt_k<<<dim3(4096, 3), dim3(256), 0, stream>>>(query, keys, values, Xq, Xk, Xv);

  // projections (bf16 A). V written transposed per batch.
  gemm_k<false, false, true, false, false, false><<<dim3(4, 8, 8), blk, 0, stream>>>(
      Xq, 1024, sXT, wt_q, 1024, 0, Qb, 1024, sXT, bq, 1.f, nullptr, 1024);
  gemm_k<false, false, true, false, false, false><<<dim3(4, 8, 8), blk, 0, stream>>>(
      Xk, 1024, sXT, wt_k, 1024, 0, Kb, 1024, sXT, bk, 1.f, nullptr, 1024);
  gemm_k<false, true, true, false, false, false><<<dim3(4, 8, 8), blk, 0, stream>>>(
      Xv, 1024, sXT, wt_v, 1024, 0, Vt, 2048, 1024l * 2048, bv, 1.f, nullptr, 1024);

  // scores: S[b][t][s] = Q[b] K[b]^T / 32, upper tiles skipped when masked
  gemm_k<true, false, false, true, true, false><<<dim3(8, 8, 8), blk, 0, stream>>>(
      Qb, 1024, sXT, Kb, 1024, sXT, S, 2048, 2048l * 2048, nullptr, 0.03125f, maskp, 1024);

  // softmax rows -> bf16 P in place (stride 4096 elems)
  softmax_k<<<dim3(16384), dim3(256), 0, stream>>>(S, maskp);

  // context[b][t][d] = P[b] @ V[b]  (A = P bf16, lda 4096; Bt = Vt; K causal-clamped)
  gemm_k<false, false, false, false, false, true><<<dim3(4, 8, 8), blk, 0, stream>>>(
      (unsigned short*)S, 4096, 2048l * 4096, Vt, 2048, 1024l * 2048,
      ctx, 1024, sXT, nullptr, 1.f, maskp, 2048);

  // out = context @ Wo + bo (f32 out)
  gemm_k<true, false, true, false, false, false><<<dim3(4, 8, 8), blk, 0, stream>>>(
      ctx, 1024, sXT, wt_o, 1024, 0, out, 1024, sXT, bo, 1.f, nullptr, 1024);
}

// Round 7
// 354.411 us; speedup vs baseline: 1.2150x; 1.0560x over previous
//
#include <hip/hip_runtime.h>
#include <hip/hip_bf16.h>

// ScaledDotAttention: out = softmax_causal((X Wq)(X Wk)^T / 32) (X Wv) Wo + bo
// B=8, T=2048, D=DK=DV=1024. bf16 MFMA pipeline, materialized S/P in ws.
// R7: fused f32->bf16 A-staging inside the 4-phase gemm (A_F32 variant:
//     load f32 regs in phase A, cvt_pk + swizzled ds_write in phase C,
//     lgkm drain end of phase D). Eliminates the 72us cvt_k pass.
//     bf16-A path keeps the R6 schedule verbatim (vmcnt(4) gates).

typedef __attribute__((ext_vector_type(8))) short bf16x8;
typedef __attribute__((ext_vector_type(4))) float f32x4;

#define DEVI __device__ __forceinline__
#define VM_GATE(n) asm volatile("s_waitcnt vmcnt(" #n ")" ::: "memory")
#define LGKM0()    asm volatile("s_waitcnt lgkmcnt(0)" ::: "memory")

DEVI unsigned short f2bf(float f) {
  union { float f; unsigned u; } v; v.f = f;
  unsigned r = v.u + 0x7FFFu + ((v.u >> 16) & 1u);
  return (unsigned short)(r >> 16);
}

DEVI unsigned pkbf(float a, float b) {
  unsigned r;
  asm("v_cvt_pk_bf16_f32 %0, %1, %2" : "=v"(r) : "v"(a), "v"(b));
  return r;  // lo16 = bf16(a), hi16 = bf16(b)
}

DEVI void load_lds16(const void* g, void* l) {
  __builtin_amdgcn_global_load_lds(
      (const __attribute__((address_space(1))) unsigned int*)g,
      (__attribute__((address_space(3))) unsigned int*)l,
      16, 0, 0);
}

constexpr int BM = 256, BN = 256, BK = 64;

// Stage one 16KB chunk ([256 rows][32 K] bf16) = 2 global_load_lds per thread.
// LDS linear tloc=(r*4+ps) holds global k-slot q=(ps-(r>>1))&3 (inverse of the
// read-side permutation slot'=(q+(r>>1))&3).
DEVI void stage_chunk(char* chunk, const unsigned short* src, long ldx,
                      int kbase, int tid) {
#pragma unroll
  for (int i = 0; i < 2; ++i) {
    int tloc = i * 512 + tid;
    int r = tloc >> 2, ps = tloc & 3;
    int q = (ps - (r >> 1)) & 3;
    load_lds16(src + (size_t)r * ldx + kbase + q * 8,
               chunk + (i * 512 + (tid & 0x1C0)) * 16);
  }
}

// read one 16B fragment at row r, k-group q0 from a chunk
DEVI bf16x8 frag(const char* chunk, int r, int q0) {
  int sp = (q0 + (r >> 1)) & 3;
  return *(const bf16x8*)(chunk + r * 64 + sp * 16);
}

// f32 A-tile helpers: 2048 cells (r, q) of 8 floats; 4 cells per thread.
DEVI void a32_load(float4* fr, const float* src, long lda, int kbase, int tid) {
#pragma unroll
  for (int j = 0; j < 4; ++j) {
    int cell = j * 512 + tid;
    int r = cell >> 3, q = cell & 7;
    const float* p = src + (size_t)r * lda + kbase + q * 8;
    fr[2 * j]     = *(const float4*)p;
    fr[2 * j + 1] = *(const float4*)(p + 4);
  }
}
DEVI void a32_write(char* chunk0, char* chunk1, const float4* fr, int tid) {
#pragma unroll
  for (int j = 0; j < 4; ++j) {
    int cell = j * 512 + tid;
    int r = cell >> 3, q = cell & 7;
    int kh = q >> 2, qq = q & 3;
    int sp = (qq + (r >> 1)) & 3;
    uint4 u;
    u.x = pkbf(fr[2 * j].x,     fr[2 * j].y);
    u.y = pkbf(fr[2 * j].z,     fr[2 * j].w);
    u.z = pkbf(fr[2 * j + 1].x, fr[2 * j + 1].y);
    u.w = pkbf(fr[2 * j + 1].z, fr[2 * j + 1].w);
    *(uint4*)((kh ? chunk1 : chunk0) + r * 64 + sp * 16) = u;
  }
}

// C[M][N] = A[M][K] * Bt[N][K]^T  (A bf16 or f32; Bt bf16 row=n contiguous k)
template<bool A_F32, bool OUT_F32, bool OUT_TRANS, bool DO_BIAS, bool DO_SCALE,
         bool DO_CSKIP, bool DO_KCLAMP>
__global__ __launch_bounds__(512, 2) void gemm_k(
    const void* __restrict__ Ap, long lda, long sAz,
    const unsigned short* __restrict__ Bt, long ldb, long sBz,
    void* __restrict__ Cp, long ldc, long sCz,
    const float* __restrict__ bias, float scale,
    const int* __restrict__ maskp, int Kdim)
{
  // bijective XCD-chunked block swizzle (all grids have nwg % 8 == 0)
  const int nx = gridDim.x, ny = gridDim.y;
  int bid = (blockIdx.z * ny + blockIdx.y) * nx + blockIdx.x;
  const int nwg = nx * ny * (int)gridDim.z;
  if ((nwg & 7) == 0) bid = (bid & 7) * (nwg >> 3) + (bid >> 3);
  const int bx = bid % nx;
  const int t1 = bid / nx;
  const int by = t1 % ny;
  const int z  = t1 / ny;

  const int n0 = bx * BN;
  const int m0 = by * BM;
  if constexpr (DO_CSKIP) {
    if (maskp[0] && n0 > m0 + (BM - 1)) return;  // tile fully above diagonal
  }
  int Keff = Kdim;
  if constexpr (DO_KCLAMP) {
    if (maskp[0]) Keff = min(Kdim, m0 + BM);     // P lower-triangular
  }

  // [buf][tensor A=0/B=1][k-half][16KB]
  __shared__ alignas(16) char LDSb[2][2][2][16384];

  const int tid  = threadIdx.x;
  const int lane = tid & 63;
  const int w    = tid >> 6;
  const int wr   = w >> 2, wc = w & 3;   // 2x4 waves; per-wave 128(M) x 64(N)
  const int la   = lane & 15;
  const int q0   = lane >> 4;

  f32x4 acc[8][4];
  const f32x4 z4 = {0.f, 0.f, 0.f, 0.f};
#pragma unroll
  for (int mi = 0; mi < 8; ++mi)
#pragma unroll
    for (int ni = 0; ni < 4; ++ni) acc[mi][ni] = z4;

  const unsigned short* Ag0 = (const unsigned short*)Ap + (size_t)z * sAz + (size_t)m0 * lda;
  const float*          Af0 = (const float*)Ap + (size_t)z * sAz + (size_t)m0 * lda;
  const unsigned short* Bg0 = Bt + (size_t)z * sBz + (size_t)n0 * ldb;

  float4 fr[8];

  // ---- prologue: stage tile 0
  if constexpr (A_F32) {
    a32_load(fr, Af0, lda, 0, tid);                 // 8 f32 loads (oldest)
    stage_chunk((char*)LDSb[0][1][0], Bg0, ldb, 0,  tid);
    stage_chunk((char*)LDSb[0][1][1], Bg0, ldb, 32, tid);
    VM_GATE(4);                                     // A-f32 done; B's 4 fly
    a32_write((char*)LDSb[0][0][0], (char*)LDSb[0][0][1], fr, tid);
    LGKM0();
  } else {
    stage_chunk((char*)LDSb[0][0][0], Ag0, lda, 0,  tid);
    stage_chunk((char*)LDSb[0][1][0], Bg0, ldb, 0,  tid);
    stage_chunk((char*)LDSb[0][0][1], Ag0, lda, 32, tid);
    stage_chunk((char*)LDSb[0][1][1], Bg0, ldb, 32, tid);
  }

  const int nt = Keff / BK;
  for (int t = 0; t < nt; ++t) {
    const int buf = t & 1, nb = buf ^ 1;
    const bool pf = (t + 1 < nt);
    const int kb = (t + 1) * BK;
    const char* Ak0 = LDSb[buf][0][0];
    const char* Bk0 = LDSb[buf][1][0];
    const char* Ak1 = LDSb[buf][0][1];
    const char* Bk1 = LDSb[buf][1][1];
    bf16x8 bfv0[4], bfv1[4], af[4];

    // ---- phase A: kk0, mi 0-3
    if constexpr (A_F32) { VM_GATE(2); } else { VM_GATE(4); }
    __builtin_amdgcn_s_barrier();
    __builtin_amdgcn_sched_barrier(0);
#pragma unroll
    for (int ni = 0; ni < 4; ++ni) bfv0[ni] = frag(Bk0, wc * 64 + ni * 16 + la, q0);
#pragma unroll
    for (int mi = 0; mi < 4; ++mi) af[mi] = frag(Ak0, wr * 128 + mi * 16 + la, q0);
    if (pf) {
      if constexpr (A_F32) a32_load(fr, Af0, lda, kb, tid);
      else stage_chunk((char*)LDSb[nb][0][0], Ag0, lda, kb, tid);
    }
    __builtin_amdgcn_s_setprio(1);
#pragma unroll
    for (int mi = 0; mi < 4; ++mi)
#pragma unroll
      for (int ni = 0; ni < 4; ++ni)
        acc[mi][ni] = __builtin_amdgcn_mfma_f32_16x16x32_bf16(af[mi], bfv0[ni], acc[mi][ni], 0, 0, 0);
    __builtin_amdgcn_s_setprio(0);

    // ---- phase B: kk0, mi 4-7 (reuse bfv0)
    __builtin_amdgcn_s_barrier();
    __builtin_amdgcn_sched_barrier(0);
#pragma unroll
    for (int mi = 0; mi < 4; ++mi) af[mi] = frag(Ak0, wr * 128 + 64 + mi * 16 + la, q0);
    if (pf) stage_chunk((char*)LDSb[nb][1][0], Bg0, ldb, kb, tid);
    __builtin_amdgcn_s_setprio(1);
#pragma unroll
    for (int mi = 0; mi < 4; ++mi)
#pragma unroll
      for (int ni = 0; ni < 4; ++ni)
        acc[4 + mi][ni] = __builtin_amdgcn_mfma_f32_16x16x32_bf16(af[mi], bfv0[ni], acc[4 + mi][ni], 0, 0, 0);
    __builtin_amdgcn_s_setprio(0);

    // ---- phase C: kk1, mi 0-3
    if constexpr (A_F32) {
      if (pf) { VM_GATE(2); } else { VM_GATE(0); }   // B1(t) + A-f32 regs
    } else {
      if (pf) { VM_GATE(4); } else { VM_GATE(0); }
    }
    __builtin_amdgcn_s_barrier();
    __builtin_amdgcn_sched_barrier(0);
#pragma unroll
    for (int ni = 0; ni < 4; ++ni) bfv1[ni] = frag(Bk1, wc * 64 + ni * 16 + la, q0);
#pragma unroll
    for (int mi = 0; mi < 4; ++mi) af[mi] = frag(Ak1, wr * 128 + mi * 16 + la, q0);
    if (pf) {
      if constexpr (A_F32)
        a32_write((char*)LDSb[nb][0][0], (char*)LDSb[nb][0][1], fr, tid);
      else
        stage_chunk((char*)LDSb[nb][0][1], Ag0, lda, kb + 32, tid);
    }
    __builtin_amdgcn_s_setprio(1);
#pragma unroll
    for (int mi = 0; mi < 4; ++mi)
#pragma unroll
      for (int ni = 0; ni < 4; ++ni)
        acc[mi][ni] = __builtin_amdgcn_mfma_f32_16x16x32_bf16(af[mi], bfv1[ni], acc[mi][ni], 0, 0, 0);
    __builtin_amdgcn_s_setprio(0);

    // ---- phase D: kk1, mi 4-7 (reuse bfv1)
    __builtin_amdgcn_s_barrier();
    __builtin_amdgcn_sched_barrier(0);
#pragma unroll
    for (int mi = 0; mi < 4; ++mi) af[mi] = frag(Ak1, wr * 128 + 64 + mi * 16 + la, q0);
    if (pf) stage_chunk((char*)LDSb[nb][1][1], Bg0, ldb, kb + 32, tid);
    __builtin_amdgcn_s_setprio(1);
#pragma unroll
    for (int mi = 0; mi < 4; ++mi)
#pragma unroll
      for (int ni = 0; ni < 4; ++ni)
        acc[4 + mi][ni] = __builtin_amdgcn_mfma_f32_16x16x32_bf16(af[mi], bfv1[ni], acc[4 + mi][ni], 0, 0, 0);
    __builtin_amdgcn_s_setprio(0);
    if constexpr (A_F32) {
      if (pf) { LGKM0(); __builtin_amdgcn_sched_barrier(0); }  // A ds_writes drained before next barrier
    }
  }

  // epilogue: D frag (verified m89): col = lane&15, row = (lane>>4)*4 + reg
#pragma unroll
  for (int ni = 0; ni < 4; ++ni) {
    const int n = n0 + wc * 64 + ni * 16 + la;
    float bv = 0.f;
    if constexpr (DO_BIAS) bv = bias[n];
#pragma unroll
    for (int mi = 0; mi < 8; ++mi) {
      const int m = m0 + wr * 128 + mi * 16 + (q0 << 2);
      f32x4 c = acc[mi][ni];
      if constexpr (DO_SCALE) c = c * scale;
      if constexpr (DO_BIAS)  c = c + bv;
      if constexpr (OUT_TRANS) {
        unsigned short* C = (unsigned short*)Cp + (size_t)z * sCz + (size_t)n * ldc + m;
        ushort4 h;
        h.x = f2bf(c[0]); h.y = f2bf(c[1]); h.z = f2bf(c[2]); h.w = f2bf(c[3]);
        *(ushort4*)C = h;
      } else if constexpr (OUT_F32) {
        float* C = (float*)Cp + (size_t)z * sCz + (size_t)m * ldc + n;
#pragma unroll
        for (int j = 0; j < 4; ++j) C[(size_t)j * ldc] = c[j];
      } else {
        unsigned short* C = (unsigned short*)Cp + (size_t)z * sCz + (size_t)m * ldc + n;
#pragma unroll
        for (int j = 0; j < 4; ++j) C[(size_t)j * ldc] = f2bf(c[j]);
      }
    }
  }
}

// Wt[n][k] = bf16(W[k][n]), 1024x1024, 64x64 tiles via LDS
__global__ __launch_bounds__(256) void wtrans_k(const float* __restrict__ W,
                                                unsigned short* __restrict__ Wt)
{
  __shared__ unsigned short L[64][80];  // 160B row stride, 16B aligned
  const int n0 = blockIdx.x * 64, k0 = blockIdx.y * 64;
  const int tid = threadIdx.x;
#pragma unroll
  for (int p = 0; p < 4; ++p) {
    int idx = tid + p * 256;
    int r = idx >> 4, c4 = idx & 15;
    float4 v = *(const float4*)(W + (size_t)(k0 + r) * 1024 + n0 + c4 * 4);
    L[c4 * 4 + 0][r] = f2bf(v.x);
    L[c4 * 4 + 1][r] = f2bf(v.y);
    L[c4 * 4 + 2][r] = f2bf(v.z);
    L[c4 * 4 + 3][r] = f2bf(v.w);
  }
  __syncthreads();
#pragma unroll
  for (int p = 0; p < 2; ++p) {
    int idx = tid + p * 256;
    int n = idx >> 3, c8 = idx & 7;
    int4 v = *(const int4*)(&L[n][c8 * 8]);
    *(int4*)(Wt + (size_t)(n0 + n) * 1024 + k0 + c8 * 8) = v;
  }
}

// row softmax over S[16384][2048] f32; writes bf16 P in place (row-start).
// Causal: read only cols < lim; write zeros up to the 256-tile boundary
// (PV's K-clamp with BM=256 never reads beyond it).
__global__ __launch_bounds__(256) void softmax_k(float* __restrict__ S,
                                                 const int* __restrict__ maskp)
{
  const int row = blockIdx.x;
  const int t = row & 2047;
  const int msk = maskp[0];
  const int lim  = msk ? (t + 1) : 2048;
  const int wlim = msk ? ((t & ~255) + 256) : 2048;
  float* Srow = S + (size_t)row * 2048;
  const int tid = threadIdx.x;
  const int cbase = tid * 8;

  float v[8];
  if (cbase < lim) {
    float4 a = *(const float4*)(Srow + cbase);
    float4 b = *(const float4*)(Srow + cbase + 4);
    v[0] = a.x; v[1] = a.y; v[2] = a.z; v[3] = a.w;
    v[4] = b.x; v[5] = b.y; v[6] = b.z; v[7] = b.w;
#pragma unroll
    for (int j = 0; j < 8; ++j)
      if (cbase + j >= lim) v[j] = -__builtin_inff();
  } else {
#pragma unroll
    for (int j = 0; j < 8; ++j) v[j] = -__builtin_inff();
  }

  float mx = v[0];
#pragma unroll
  for (int j = 1; j < 8; ++j) mx = fmaxf(mx, v[j]);
#pragma unroll
  for (int off = 32; off; off >>= 1) mx = fmaxf(mx, __shfl_xor(mx, off, 64));

  __shared__ float redm[4], reds[4];
  const int wid = tid >> 6;
  if ((tid & 63) == 0) redm[wid] = mx;
  __syncthreads();  // also orders all row loads before the in-place write below
  mx = fmaxf(fmaxf(redm[0], redm[1]), fmaxf(redm[2], redm[3]));

  float e[8], s = 0.f;
#pragma unroll
  for (int j = 0; j < 8; ++j) { e[j] = __expf(v[j] - mx); s += e[j]; }
#pragma unroll
  for (int off = 32; off; off >>= 1) s += __shfl_xor(s, off, 64);
  if ((tid & 63) == 0) reds[wid] = s;
  __syncthreads();
  s = reds[0] + reds[1] + reds[2] + reds[3];
  const float inv = 1.0f / s;

  if (cbase < wlim) {
    unsigned short* Prow = (unsigned short*)Srow;
    unsigned pk[4];
#pragma unroll
    for (int q = 0; q < 4; ++q)
      pk[q] = (unsigned)f2bf(e[2 * q] * inv) | ((unsigned)f2bf(e[2 * q + 1] * inv) << 16);
    int4 o; o.x = (int)pk[0]; o.y = (int)pk[1]; o.z = (int)pk[2]; o.w = (int)pk[3];
    *(int4*)(Prow + (size_t)cbase) = o;
  }
}

extern "C" void kernel_launch(void* const* d_in, const int* in_sizes, int n_in,
                              void* d_out, int out_size, void* d_ws, size_t ws_size,
                              hipStream_t stream)
{
  const float* query  = (const float*)d_in[0];
  const float* keys   = (const float*)d_in[1];
  const float* values = (const float*)d_in[2];
  const float* Wq = (const float*)d_in[3];
  const float* bq = (const float*)d_in[4];
  const float* Wk = (const float*)d_in[5];
  const float* bk = (const float*)d_in[6];
  const float* Wv = (const float*)d_in[7];
  const float* bv = (const float*)d_in[8];
  const float* Wo = (const float*)d_in[9];
  const float* bo = (const float*)d_in[10];
  const int* maskp = (const int*)d_in[11];
  float* out = (float*)d_out;

  char* ws = (char*)d_ws;
  const size_t MB = 1ull << 20;
  unsigned short* wt_q = (unsigned short*)(ws + 0 * MB);
  unsigned short* wt_k = (unsigned short*)(ws + 2 * MB);
  unsigned short* wt_v = (unsigned short*)(ws + 4 * MB);
  unsigned short* wt_o = (unsigned short*)(ws + 6 * MB);
  unsigned short* Qb   = (unsigned short*)(ws + 8 * MB);    // 32 MiB [16384][1024]
  unsigned short* Kb   = (unsigned short*)(ws + 40 * MB);   // 32 MiB
  unsigned short* Vt   = (unsigned short*)(ws + 72 * MB);   // 32 MiB [8][1024][2048]
  float*          S    = (float*)(ws + 104 * MB);           // 128 MiB [16384][2048]
  unsigned short* ctx  = Qb;  // context aliases Q (Q dead after scores)

  const dim3 blk(512);
  const long sXT = 2048l * 1024;   // per-batch stride of [T,1024] tensors

  // weight transpose+convert
  wtrans_k<<<dim3(16, 16), dim3(256), 0, stream>>>(Wq, wt_q);
  wtrans_k<<<dim3(16, 16), dim3(256), 0, stream>>>(Wk, wt_k);
  wtrans_k<<<dim3(16, 16), dim3(256), 0, stream>>>(Wv, wt_v);
  wtrans_k<<<dim3(16, 16), dim3(256), 0, stream>>>(Wo, wt_o);

  // projections (A = f32 input, fused cvt). V written transposed per batch.
  gemm_k<true, false, false, true, false, false, false><<<dim3(4, 8, 8), blk, 0, stream>>>(
      query, 1024, sXT, wt_q, 1024, 0, Qb, 1024, sXT, bq, 1.f, nullptr, 1024);
  gemm_k<true, false, false, true, false, false, false><<<dim3(4, 8, 8), blk, 0, stream>>>(
      keys, 1024, sXT, wt_k, 1024, 0, Kb, 1024, sXT, bk, 1.f, nullptr, 1024);
  gemm_k<true, false, true, true, false, false, false><<<dim3(4, 8, 8), blk, 0, stream>>>(
      values, 1024, sXT, wt_v, 1024, 0, Vt, 2048, 1024l * 2048, bv, 1.f, nullptr, 1024);

  // scores: S[b][t][s] = Q[b] K[b]^T / 32, upper tiles skipped when masked
  gemm_k<false, true, false, false, true, true, false><<<dim3(8, 8, 8), blk, 0, stream>>>(
      Qb, 1024, sXT, Kb, 1024, sXT, S, 2048, 2048l * 2048, nullptr, 0.03125f, maskp, 1024);

  // softmax rows -> bf16 P in place (stride 4096 elems)
  softmax_k<<<dim3(16384), dim3(256), 0, stream>>>(S, maskp);

  // context[b][t][d] = P[b] @ V[b]  (A = P bf16, lda 4096; Bt = Vt; K causal-clamped)
  gemm_k<false, false, false, false, false, false, true><<<dim3(4, 8, 8), blk, 0, stream>>>(
      (unsigned short*)S, 4096, 2048l * 4096, Vt, 2048, 1024l * 2048,
      ctx, 1024, sXT, nullptr, 1.f, maskp, 2048);

  // out = context @ Wo + bo (f32 out)
  gemm_k<false, true, false, true, false, false, false><<<dim3(4, 8, 8), blk, 0, stream>>>(
      ctx, 1024, sXT, wt_o, 1024, 0, out, 1024, sXT, bo, 1.f, nullptr, 1024);
}

// Round 8
// 326.940 us; speedup vs baseline: 1.3171x; 1.0840x over previous
//
#include <hip/hip_runtime.h>
#include <hip/hip_bf16.h>

// ScaledDotAttention: out = softmax_causal((X Wq)(X Wk)^T / 32) (X Wv) Wo + bo
// B=8, T=2048, D=DK=DV=1024. bf16 MFMA pipeline, materialized S/P in ws.
// R8: 2 phases per K-tile (32 MFMA per barrier, half the barriers of R7),
//     counted-vmcnt gates re-derived per path; A_F32 reg-loads issued one
//     full tile ahead; wtrans merged into one launch.

typedef __attribute__((ext_vector_type(8))) short bf16x8;
typedef __attribute__((ext_vector_type(4))) float f32x4;

#define DEVI __device__ __forceinline__
#define VM_GATE(n) asm volatile("s_waitcnt vmcnt(" #n ")" ::: "memory")
#define LGKM0()    asm volatile("s_waitcnt lgkmcnt(0)" ::: "memory")

DEVI unsigned short f2bf(float f) {
  union { float f; unsigned u; } v; v.f = f;
  unsigned r = v.u + 0x7FFFu + ((v.u >> 16) & 1u);
  return (unsigned short)(r >> 16);
}

DEVI unsigned pkbf(float a, float b) {
  unsigned r;
  asm("v_cvt_pk_bf16_f32 %0, %1, %2" : "=v"(r) : "v"(a), "v"(b));
  return r;
}

DEVI void load_lds16(const void* g, void* l) {
  __builtin_amdgcn_global_load_lds(
      (const __attribute__((address_space(1))) unsigned int*)g,
      (__attribute__((address_space(3))) unsigned int*)l,
      16, 0, 0);
}

constexpr int BM = 256, BN = 256, BK = 64;

// Stage one 16KB chunk ([256 rows][32 K] bf16) = 2 global_load_lds per thread.
DEVI void stage_chunk(char* chunk, const unsigned short* src, long ldx,
                      int kbase, int tid) {
#pragma unroll
  for (int i = 0; i < 2; ++i) {
    int tloc = i * 512 + tid;
    int r = tloc >> 2, ps = tloc & 3;
    int q = (ps - (r >> 1)) & 3;
    load_lds16(src + (size_t)r * ldx + kbase + q * 8,
               chunk + (i * 512 + (tid & 0x1C0)) * 16);
  }
}

// read one 16B fragment at row r, k-group q0 from a chunk
DEVI bf16x8 frag(const char* chunk, int r, int q0) {
  int sp = (q0 + (r >> 1)) & 3;
  return *(const bf16x8*)(chunk + r * 64 + sp * 16);
}

// f32 A-tile helpers: 2048 cells (r, q) of 8 floats; 4 cells per thread.
DEVI void a32_load(float4* fr, const float* src, long lda, int kbase, int tid) {
#pragma unroll
  for (int j = 0; j < 4; ++j) {
    int cell = j * 512 + tid;
    int r = cell >> 3, q = cell & 7;
    const float* p = src + (size_t)r * lda + kbase + q * 8;
    fr[2 * j]     = *(const float4*)p;
    fr[2 * j + 1] = *(const float4*)(p + 4);
  }
}
DEVI void a32_write(char* chunk0, char* chunk1, const float4* fr, int tid) {
#pragma unroll
  for (int j = 0; j < 4; ++j) {
    int cell = j * 512 + tid;
    int r = cell >> 3, q = cell & 7;
    int kh = q >> 2, qq = q & 3;
    int sp = (qq + (r >> 1)) & 3;
    uint4 u;
    u.x = pkbf(fr[2 * j].x,     fr[2 * j].y);
    u.y = pkbf(fr[2 * j].z,     fr[2 * j].w);
    u.z = pkbf(fr[2 * j + 1].x, fr[2 * j + 1].y);
    u.w = pkbf(fr[2 * j + 1].z, fr[2 * j + 1].w);
    *(uint4*)((kh ? chunk1 : chunk0) + r * 64 + sp * 16) = u;
  }
}

// C[M][N] = A[M][K] * Bt[N][K]^T  (A bf16 or f32; Bt bf16 row=n contiguous k)
template<bool A_F32, bool OUT_F32, bool OUT_TRANS, bool DO_BIAS, bool DO_SCALE,
         bool DO_CSKIP, bool DO_KCLAMP>
__global__ __launch_bounds__(512, 2) void gemm_k(
    const void* __restrict__ Ap, long lda, long sAz,
    const unsigned short* __restrict__ Bt, long ldb, long sBz,
    void* __restrict__ Cp, long ldc, long sCz,
    const float* __restrict__ bias, float scale,
    const int* __restrict__ maskp, int Kdim)
{
  // bijective XCD-chunked block swizzle (all grids have nwg % 8 == 0)
  const int nx = gridDim.x, ny = gridDim.y;
  int bid = (blockIdx.z * ny + blockIdx.y) * nx + blockIdx.x;
  const int nwg = nx * ny * (int)gridDim.z;
  if ((nwg & 7) == 0) bid = (bid & 7) * (nwg >> 3) + (bid >> 3);
  const int bx = bid % nx;
  const int t1 = bid / nx;
  const int by = t1 % ny;
  const int z  = t1 / ny;

  const int n0 = bx * BN;
  const int m0 = by * BM;
  if constexpr (DO_CSKIP) {
    if (maskp[0] && n0 > m0 + (BM - 1)) return;  // tile fully above diagonal
  }
  int Keff = Kdim;
  if constexpr (DO_KCLAMP) {
    if (maskp[0]) Keff = min(Kdim, m0 + BM);     // P lower-triangular
  }

  // [buf][tensor A=0/B=1][k-half][16KB]
  __shared__ alignas(16) char LDSb[2][2][2][16384];

  const int tid  = threadIdx.x;
  const int lane = tid & 63;
  const int w    = tid >> 6;
  const int wr   = w >> 2, wc = w & 3;   // 2x4 waves; per-wave 128(M) x 64(N)
  const int la   = lane & 15;
  const int q0   = lane >> 4;

  f32x4 acc[8][4];
  const f32x4 z4 = {0.f, 0.f, 0.f, 0.f};
#pragma unroll
  for (int mi = 0; mi < 8; ++mi)
#pragma unroll
    for (int ni = 0; ni < 4; ++ni) acc[mi][ni] = z4;

  const unsigned short* Ag0 = (const unsigned short*)Ap + (size_t)z * sAz + (size_t)m0 * lda;
  const float*          Af0 = (const float*)Ap + (size_t)z * sAz + (size_t)m0 * lda;
  const unsigned short* Bg0 = Bt + (size_t)z * sBz + (size_t)n0 * ldb;

  const int nt = Keff / BK;
  float4 fr[8];

  // ---- prologue: stage tile 0 (+ issue Aregs(1) for A_F32)
  if constexpr (A_F32) {
    a32_load(fr, Af0, lda, 0, tid);                 // Aregs(0): 8 loads
    stage_chunk((char*)LDSb[0][1][0], Bg0, ldb, 0,  tid);   // BK0(0): 2
    stage_chunk((char*)LDSb[0][1][1], Bg0, ldb, 32, tid);   // BK1(0): 2
    VM_GATE(4);                                     // Aregs(0) done; B's fly
    a32_write((char*)LDSb[0][0][0], (char*)LDSb[0][0][1], fr, tid);
    if (nt > 1) a32_load(fr, Af0, lda, BK, tid);    // Aregs(1): 8
    LGKM0();                                        // own ds_writes drained
  } else {
    stage_chunk((char*)LDSb[0][0][0], Ag0, lda, 0,  tid);
    stage_chunk((char*)LDSb[0][1][0], Bg0, ldb, 0,  tid);
    stage_chunk((char*)LDSb[0][0][1], Ag0, lda, 32, tid);
    stage_chunk((char*)LDSb[0][1][1], Bg0, ldb, 32, tid);
  }

  for (int t = 0; t < nt; ++t) {
    const int buf = t & 1, nb = buf ^ 1;
    const bool pf = (t + 1 < nt);
    const int kb = (t + 1) * BK;
    const char* Ak0 = LDSb[buf][0][0];
    const char* Bk0 = LDSb[buf][1][0];
    const char* Ak1 = LDSb[buf][0][1];
    const char* Bk1 = LDSb[buf][1][1];
    bf16x8 bfv[4], af[8];

    // ======== phase 1: kk0, mi 0..7 (32 MFMA) ========
    if constexpr (A_F32) {
      if (pf) { VM_GATE(10); } else { VM_GATE(2); }   // wait BK0(t)
    } else {
      VM_GATE(4);                                     // wait AK0(t),BK0(t)
    }
    __builtin_amdgcn_s_barrier();
    __builtin_amdgcn_sched_barrier(0);
#pragma unroll
    for (int ni = 0; ni < 4; ++ni) bfv[ni] = frag(Bk0, wc * 64 + ni * 16 + la, q0);
#pragma unroll
    for (int mi = 0; mi < 8; ++mi) af[mi] = frag(Ak0, wr * 128 + mi * 16 + la, q0);
    if (pf) {
      if constexpr (!A_F32) stage_chunk((char*)LDSb[nb][0][0], Ag0, lda, kb, tid);
      stage_chunk((char*)LDSb[nb][1][0], Bg0, ldb, kb, tid);
    }
    __builtin_amdgcn_s_setprio(1);
#pragma unroll
    for (int mi = 0; mi < 8; ++mi)
#pragma unroll
      for (int ni = 0; ni < 4; ++ni)
        acc[mi][ni] = __builtin_amdgcn_mfma_f32_16x16x32_bf16(af[mi], bfv[ni], acc[mi][ni], 0, 0, 0);
    __builtin_amdgcn_s_setprio(0);

    // ======== phase 2: kk1, mi 0..7 (32 MFMA) ========
    if constexpr (A_F32) {
      if (pf) { VM_GATE(10); } else { VM_GATE(0); }   // wait BK1(t)
    } else {
      if (pf) { VM_GATE(4); } else { VM_GATE(0); }    // wait AK1(t),BK1(t)
    }
    __builtin_amdgcn_s_barrier();
    __builtin_amdgcn_sched_barrier(0);
#pragma unroll
    for (int ni = 0; ni < 4; ++ni) bfv[ni] = frag(Bk1, wc * 64 + ni * 16 + la, q0);
#pragma unroll
    for (int mi = 0; mi < 8; ++mi) af[mi] = frag(Ak1, wr * 128 + mi * 16 + la, q0);
    if (pf) {
      if constexpr (!A_F32) stage_chunk((char*)LDSb[nb][0][1], Ag0, lda, kb + 32, tid);
      stage_chunk((char*)LDSb[nb][1][1], Bg0, ldb, kb + 32, tid);
      if constexpr (A_F32) {
        VM_GATE(4);                                   // Aregs(t+1) done
        a32_write((char*)LDSb[nb][0][0], (char*)LDSb[nb][0][1], fr, tid);
        if (t + 2 < nt) a32_load(fr, Af0, lda, kb + BK, tid);  // Aregs(t+2)
      }
    }
    __builtin_amdgcn_s_setprio(1);
#pragma unroll
    for (int mi = 0; mi < 8; ++mi)
#pragma unroll
      for (int ni = 0; ni < 4; ++ni)
        acc[mi][ni] = __builtin_amdgcn_mfma_f32_16x16x32_bf16(af[mi], bfv[ni], acc[mi][ni], 0, 0, 0);
    __builtin_amdgcn_s_setprio(0);
    if constexpr (A_F32) {
      if (pf) { LGKM0(); __builtin_amdgcn_sched_barrier(0); }
    }
  }

  // epilogue: D frag (verified m89): col = lane&15, row = (lane>>4)*4 + reg
#pragma unroll
  for (int ni = 0; ni < 4; ++ni) {
    const int n = n0 + wc * 64 + ni * 16 + la;
    float bv = 0.f;
    if constexpr (DO_BIAS) bv = bias[n];
#pragma unroll
    for (int mi = 0; mi < 8; ++mi) {
      const int m = m0 + wr * 128 + mi * 16 + (q0 << 2);
      f32x4 c = acc[mi][ni];
      if constexpr (DO_SCALE) c = c * scale;
      if constexpr (DO_BIAS)  c = c + bv;
      if constexpr (OUT_TRANS) {
        unsigned short* C = (unsigned short*)Cp + (size_t)z * sCz + (size_t)n * ldc + m;
        ushort4 h;
        h.x = f2bf(c[0]); h.y = f2bf(c[1]); h.z = f2bf(c[2]); h.w = f2bf(c[3]);
        *(ushort4*)C = h;
      } else if constexpr (OUT_F32) {
        float* C = (float*)Cp + (size_t)z * sCz + (size_t)m * ldc + n;
#pragma unroll
        for (int j = 0; j < 4; ++j) C[(size_t)j * ldc] = c[j];
      } else {
        unsigned short* C = (unsigned short*)Cp + (size_t)z * sCz + (size_t)m * ldc + n;
#pragma unroll
        for (int j = 0; j < 4; ++j) C[(size_t)j * ldc] = f2bf(c[j]);
      }
    }
  }
}

// Wt[n][k] = bf16(W[k][n]), 4 weight matrices, z selects which
__global__ __launch_bounds__(256) void wtrans_k(
    const float* __restrict__ W0, const float* __restrict__ W1,
    const float* __restrict__ W2, const float* __restrict__ W3,
    unsigned short* __restrict__ T0, unsigned short* __restrict__ T1,
    unsigned short* __restrict__ T2, unsigned short* __restrict__ T3)
{
  const float* W = blockIdx.z == 0 ? W0 : blockIdx.z == 1 ? W1
                 : blockIdx.z == 2 ? W2 : W3;
  unsigned short* Wt = blockIdx.z == 0 ? T0 : blockIdx.z == 1 ? T1
                     : blockIdx.z == 2 ? T2 : T3;
  __shared__ unsigned short L[64][80];
  const int n0 = blockIdx.x * 64, k0 = blockIdx.y * 64;
  const int tid = threadIdx.x;
#pragma unroll
  for (int p = 0; p < 4; ++p) {
    int idx = tid + p * 256;
    int r = idx >> 4, c4 = idx & 15;
    float4 v = *(const float4*)(W + (size_t)(k0 + r) * 1024 + n0 + c4 * 4);
    L[c4 * 4 + 0][r] = f2bf(v.x);
    L[c4 * 4 + 1][r] = f2bf(v.y);
    L[c4 * 4 + 2][r] = f2bf(v.z);
    L[c4 * 4 + 3][r] = f2bf(v.w);
  }
  __syncthreads();
#pragma unroll
  for (int p = 0; p < 2; ++p) {
    int idx = tid + p * 256;
    int n = idx >> 3, c8 = idx & 7;
    int4 v = *(const int4*)(&L[n][c8 * 8]);
    *(int4*)(Wt + (size_t)(n0 + n) * 1024 + k0 + c8 * 8) = v;
  }
}

// row softmax over S[16384][2048] f32; writes bf16 P in place (row-start).
// Causal: read only cols < lim; write zeros up to the 256-tile boundary
// (PV's K-clamp with BM=256 never reads beyond it).
__global__ __launch_bounds__(256) void softmax_k(float* __restrict__ S,
                                                 const int* __restrict__ maskp)
{
  const int row = blockIdx.x;
  const int t = row & 2047;
  const int msk = maskp[0];
  const int lim  = msk ? (t + 1) : 2048;
  const int wlim = msk ? ((t & ~255) + 256) : 2048;
  float* Srow = S + (size_t)row * 2048;
  const int tid = threadIdx.x;
  const int cbase = tid * 8;

  float v[8];
  if (cbase < lim) {
    float4 a = *(const float4*)(Srow + cbase);
    float4 b = *(const float4*)(Srow + cbase + 4);
    v[0] = a.x; v[1] = a.y; v[2] = a.z; v[3] = a.w;
    v[4] = b.x; v[5] = b.y; v[6] = b.z; v[7] = b.w;
#pragma unroll
    for (int j = 0; j < 8; ++j)
      if (cbase + j >= lim) v[j] = -__builtin_inff();
  } else {
#pragma unroll
    for (int j = 0; j < 8; ++j) v[j] = -__builtin_inff();
  }

  float mx = v[0];
#pragma unroll
  for (int j = 1; j < 8; ++j) mx = fmaxf(mx, v[j]);
#pragma unroll
  for (int off = 32; off; off >>= 1) mx = fmaxf(mx, __shfl_xor(mx, off, 64));

  __shared__ float redm[4], reds[4];
  const int wid = tid >> 6;
  if ((tid & 63) == 0) redm[wid] = mx;
  __syncthreads();
  mx = fmaxf(fmaxf(redm[0], redm[1]), fmaxf(redm[2], redm[3]));

  float e[8], s = 0.f;
#pragma unroll
  for (int j = 0; j < 8; ++j) { e[j] = __expf(v[j] - mx); s += e[j]; }
#pragma unroll
  for (int off = 32; off; off >>= 1) s += __shfl_xor(s, off, 64);
  if ((tid & 63) == 0) reds[wid] = s;
  __syncthreads();
  s = reds[0] + reds[1] + reds[2] + reds[3];
  const float inv = 1.0f / s;

  if (cbase < wlim) {
    unsigned short* Prow = (unsigned short*)Srow;
    unsigned pk[4];
#pragma unroll
    for (int q = 0; q < 4; ++q)
      pk[q] = (unsigned)f2bf(e[2 * q] * inv) | ((unsigned)f2bf(e[2 * q + 1] * inv) << 16);
    int4 o; o.x = (int)pk[0]; o.y = (int)pk[1]; o.z = (int)pk[2]; o.w = (int)pk[3];
    *(int4*)(Prow + (size_t)cbase) = o;
  }
}

extern "C" void kernel_launch(void* const* d_in, const int* in_sizes, int n_in,
                              void* d_out, int out_size, void* d_ws, size_t ws_size,
                              hipStream_t stream)
{
  const float* query  = (const float*)d_in[0];
  const float* keys   = (const float*)d_in[1];
  const float* values = (const float*)d_in[2];
  const float* Wq = (const float*)d_in[3];
  const float* bq = (const float*)d_in[4];
  const float* Wk = (const float*)d_in[5];
  const float* bk = (const float*)d_in[6];
  const float* Wv = (const float*)d_in[7];
  const float* bv = (const float*)d_in[8];
  const float* Wo = (const float*)d_in[9];
  const float* bo = (const float*)d_in[10];
  const int* maskp = (const int*)d_in[11];
  float* out = (float*)d_out;

  char* ws = (char*)d_ws;
  const size_t MB = 1ull << 20;
  unsigned short* wt_q = (unsigned short*)(ws + 0 * MB);
  unsigned short* wt_k = (unsigned short*)(ws + 2 * MB);
  unsigned short* wt_v = (unsigned short*)(ws + 4 * MB);
  unsigned short* wt_o = (unsigned short*)(ws + 6 * MB);
  unsigned short* Qb   = (unsigned short*)(ws + 8 * MB);    // 32 MiB [16384][1024]
  unsigned short* Kb   = (unsigned short*)(ws + 40 * MB);   // 32 MiB
  unsigned short* Vt   = (unsigned short*)(ws + 72 * MB);   // 32 MiB [8][1024][2048]
  float*          S    = (float*)(ws + 104 * MB);           // 128 MiB [16384][2048]
  unsigned short* ctx  = Qb;  // context aliases Q (Q dead after scores)

  const dim3 blk(512);
  const long sXT = 2048l * 1024;   // per-batch stride of [T,1024] tensors

  // weight transpose+convert (one launch, z = which matrix)
  wtrans_k<<<dim3(16, 16, 4), dim3(256), 0, stream>>>(
      Wq, Wk, Wv, Wo, wt_q, wt_k, wt_v, wt_o);

  // projections (A = f32 input, fused cvt). V written transposed per batch.
  gemm_k<true, false, false, true, false, false, false><<<dim3(4, 8, 8), blk, 0, stream>>>(
      query, 1024, sXT, wt_q, 1024, 0, Qb, 1024, sXT, bq, 1.f, nullptr, 1024);
  gemm_k<true, false, false, true, false, false, false><<<dim3(4, 8, 8), blk, 0, stream>>>(
      keys, 1024, sXT, wt_k, 1024, 0, Kb, 1024, sXT, bk, 1.f, nullptr, 1024);
  gemm_k<true, false, true, true, false, false, false><<<dim3(4, 8, 8), blk, 0, stream>>>(
      values, 1024, sXT, wt_v, 1024, 0, Vt, 2048, 1024l * 2048, bv, 1.f, nullptr, 1024);

  // scores: S[b][t][s] = Q[b] K[b]^T / 32, upper tiles skipped when masked
  gemm_k<false, true, false, false, true, true, false><<<dim3(8, 8, 8), blk, 0, stream>>>(
      Qb, 1024, sXT, Kb, 1024, sXT, S, 2048, 2048l * 2048, nullptr, 0.03125f, maskp, 1024);

  // softmax rows -> bf16 P in place (stride 4096 elems)
  softmax_k<<<dim3(16384), dim3(256), 0, stream>>>(S, maskp);

  // context[b][t][d] = P[b] @ V[b]  (A = P bf16, lda 4096; Bt = Vt; K causal-clamped)
  gemm_k<false, false, false, false, false, false, true><<<dim3(4, 8, 8), blk, 0, stream>>>(
      (unsigned short*)S, 4096, 2048l * 4096, Vt, 2048, 1024l * 2048,
      ctx, 1024, sXT, nullptr, 1.f, maskp, 2048);

  // out = context @ Wo + bo (f32 out)
  gemm_k<false, true, false, true, false, false, false><<<dim3(4, 8, 8), blk, 0, stream>>>(
      ctx, 1024, sXT, wt_o, 1024, 0, out, 1024, sXT, bo, 1.f, nullptr, 1024);
}